// Round 3
// baseline (270.967 us; speedup 1.0000x reference)
//
#include <hip/hip_runtime.h>
#include <hip/hip_bf16.h>
#include <math.h>

// Problem constants (fixed shapes)
#define BATCH   2
#define TSEQ    2048
#define DEMBED  1024
#define NHEAD   16
#define DHEAD   64
#define NGROUP  4
#define ROPEN   32
#define FQKV    1536          // (16 + 2*4) * 64
#define MROWS   (BATCH*TSEQ)  // 4096

typedef __attribute__((ext_vector_type(8))) short short8;   // 8 bf16 = 4 VGPR
typedef __attribute__((ext_vector_type(4))) float floatx4;  // MFMA C/D

// ---------------------------------------------------------------------------
// split helpers: f = hi + lo, hi = truncate-to-bf16(f), lo = bf16(f - hi).
// ---------------------------------------------------------------------------
__device__ __forceinline__ void split_pack8(const float* f, uint4& h4, uint4& l4) {
    uint u[8], lu[8];
    #pragma unroll
    for (int j = 0; j < 8; ++j) {
        u[j] = __float_as_uint(f[j]);
        float lf = f[j] - __uint_as_float(u[j] & 0xffff0000u);
        lu[j] = __float_as_uint(lf);
    }
    h4.x = __builtin_amdgcn_perm(u[1], u[0], 0x07060302u);
    h4.y = __builtin_amdgcn_perm(u[3], u[2], 0x07060302u);
    h4.z = __builtin_amdgcn_perm(u[5], u[4], 0x07060302u);
    h4.w = __builtin_amdgcn_perm(u[7], u[6], 0x07060302u);
    l4.x = __builtin_amdgcn_perm(lu[1], lu[0], 0x07060302u);
    l4.y = __builtin_amdgcn_perm(lu[3], lu[2], 0x07060302u);
    l4.z = __builtin_amdgcn_perm(lu[5], lu[4], 0x07060302u);
    l4.w = __builtin_amdgcn_perm(lu[7], lu[6], 0x07060302u);
}

// round-to-nearest bf16 pack of 8 floats -> hi-only uint4 (unbiased)
__device__ __forceinline__ void rtn_pack8(const float* f, uint4& h4) {
    uint t[8];
    #pragma unroll
    for (int j = 0; j < 8; ++j)
        t[j] = __float_as_uint(f[j]) + 0x8000u;
    h4.x = __builtin_amdgcn_perm(t[1], t[0], 0x07060302u);
    h4.y = __builtin_amdgcn_perm(t[3], t[2], 0x07060302u);
    h4.z = __builtin_amdgcn_perm(t[5], t[4], 0x07060302u);
    h4.w = __builtin_amdgcn_perm(t[7], t[6], 0x07060302u);
}

__device__ __forceinline__ ushort bf16_rtn(float x) {
    return (ushort)((__float_as_uint(x) + 0x8000u) >> 16);
}

// async 16B/lane global->LDS copy; lds must be wave-uniform (HW adds lane*16)
__device__ __forceinline__ void lds_async16(void* lds, const void* gp) {
    __builtin_amdgcn_global_load_lds(
        (const __attribute__((address_space(1))) unsigned int*)gp,
        (__attribute__((address_space(3))) unsigned int*)lds,
        16, 0, 0);
}

// ===========================================================================
// MFMA-GEMM: pre-swizzled hi/lo bf16 images.
// Image layout (A and B^T): per (tile128, kblock64):
//   [hi: 128 rows x 128B][lo: 128 rows x 128B] = 32 KB, tile index = rt*16 + c.
//   Row r holds 64 bf16 k-values as 8 chunks of 16B; chunk j at phys j^(r&7).
// ===========================================================================

// ---- x converter: [4096][1024] f32 row-major -> A-image ----
__global__ __launch_bounds__(256) void conv_xy(const float* __restrict__ in,
                                               char* __restrict__ img) {
    const int tid = threadIdx.x;
    const int c   = blockIdx.x & 15;
    const int mt  = blockIdx.x >> 4;
    const int r    = tid >> 1;
    const int half = tid & 1;

    const float* src = in + (size_t)(mt*128 + r)*1024 + c*64 + half*32;
    float f[32];
    #pragma unroll
    for (int u = 0; u < 8; ++u)
        *(float4*)(f + 4*u) = *(const float4*)(src + 4*u);

    char* tile = img + ((size_t)(mt*16 + c)) * 32768;
    #pragma unroll
    for (int cc = 0; cc < 4; ++cc) {
        uint4 h4, l4;
        split_pack8(f + cc*8, h4, l4);
        int j    = half*4 + cc;
        int phys = j ^ (r & 7);
        *(uint4*)(tile + r*128 + phys*16)         = h4;
        *(uint4*)(tile + 16384 + r*128 + phys*16) = l4;
    }
}

// ---- weight converter (transpose): W [1024][N] f32 -> B^T image ----
__global__ __launch_bounds__(256) void conv_w(const float* __restrict__ W,
                                              int N,
                                              char* __restrict__ img) {
    __shared__ float Lf[64][132];
    const int tid = threadIdx.x;
    const int c   = blockIdx.x;
    const int nt  = blockIdx.y;

    {
        const int kk = tid >> 2;
        const int nc = (tid & 3) * 32;
        const float* src = W + (size_t)(c*64 + kk)*N + nt*128 + nc;
        #pragma unroll
        for (int u = 0; u < 8; ++u)
            *(float4*)(&Lf[kk][nc + 4*u]) = *(const float4*)(src + 4*u);
    }
    __syncthreads();

    char* tile = img + ((size_t)(nt*16 + c)) * 32768;
    #pragma unroll
    for (int rep = 0; rep < 4; ++rep) {
        int idx = rep*256 + tid;
        int n = idx & 127;
        int j = idx >> 7;
        float v[8];
        #pragma unroll
        for (int i = 0; i < 8; ++i) v[i] = Lf[j*8 + i][n];
        uint4 h4, l4;
        split_pack8(v, h4, l4);
        int phys = j ^ (n & 7);
        *(uint4*)(tile + n*128 + phys*16)         = h4;
        *(uint4*)(tile + 16384 + n*128 + phys*16) = l4;
    }
}

// ---------------------------------------------------------------------------
// qkv projection with fused RoPE + K/V image epilogue.  Retiled to 64M x 128N
// (grid 12 x 64 = 768 blocks = exactly 3/CU -> balanced, 3 waves/SIMD; old
// 384-block grid left half the CUs with 2 resident blocks and half with 1).
// Waves 2x2: wm = 32-row half, wn = 64-col half; acc[2][4].
// LDS main: A hi/lo 16K | B hi/lo 32K = 48K.  Epilogue: two shared 64x67 f32
// transpose buffers (one per wn-slice), 34.4K, overlapping the main region.
// ---------------------------------------------------------------------------
__global__ __launch_bounds__(256, 3) void gemm_qkv_mfma(const char* __restrict__ Aimg,
                                                        const char* __restrict__ Bimg,
                                                        const float* __restrict__ cosp,
                                                        const float* __restrict__ sinp,
                                                        float* __restrict__ Qf,
                                                        ushort* __restrict__ Kimg,
                                                        ushort* __restrict__ Vimg) {
    __shared__ __align__(16) char smem[49152];
    const int tid = threadIdx.x;
    const int nt = blockIdx.x, mt = blockIdx.y;   // mt: 64-row tile (0..63)

    const int wv = tid >> 6;
    const int wm = wv & 1, wn = wv >> 1;
    const int lane = tid & 63;
    const int qd = lane >> 4, cl = lane & 15;
    const int wslot = (tid & 192) * 16;

    floatx4 acc[2][4];
    #pragma unroll
    for (int tm = 0; tm < 2; ++tm)
        #pragma unroll
        for (int tn = 0; tn < 4; ++tn)
            acc[tm][tn] = (floatx4){0.f, 0.f, 0.f, 0.f};

    for (int c = 0; c < 16; ++c) {
        __syncthreads();
        {
            // A 64-row half-tile: hi 8K at (mt&1)*8192, lo at +16384
            const char* sA = Aimg + ((size_t)((mt >> 1)*16 + c))*32768
                                  + (mt & 1)*8192 + (size_t)tid*16;
            const char* sB = Bimg + ((size_t)(nt*16 + c))*32768 + (size_t)tid*16;
            lds_async16(smem + wslot,          sA);
            lds_async16(smem + 4096  + wslot,  sA + 4096);
            lds_async16(smem + 8192  + wslot,  sA + 16384);
            lds_async16(smem + 12288 + wslot,  sA + 16384 + 4096);
            #pragma unroll
            for (int j = 0; j < 4; ++j) {
                lds_async16(smem + 16384 + j*4096 + wslot, sB + j*4096);
                lds_async16(smem + 32768 + j*4096 + wslot, sB + 16384 + j*4096);
            }
        }
        __syncthreads();

        #pragma unroll
        for (int s = 0; s < 2; ++s) {
            const int phys = ((s*4 + qd) ^ (cl & 7)) * 16;
            short8 ah[2], al[2], bh[4], bl[4];
            #pragma unroll
            for (int tt = 0; tt < 2; ++tt) {
                const int rA = wm*32 + 16*tt + cl;
                ah[tt] = *(const short8*)(smem + rA*128 + phys);
                al[tt] = *(const short8*)(smem + 8192 + rA*128 + phys);
            }
            #pragma unroll
            for (int tt = 0; tt < 4; ++tt) {
                const int rB = wn*64 + 16*tt + cl;
                bh[tt] = *(const short8*)(smem + 16384 + rB*128 + phys);
                bl[tt] = *(const short8*)(smem + 32768 + rB*128 + phys);
            }
            #pragma unroll
            for (int tm = 0; tm < 2; ++tm)
                #pragma unroll
                for (int tn = 0; tn < 4; ++tn) {
                    acc[tm][tn] = __builtin_amdgcn_mfma_f32_16x16x32_bf16(ah[tm], bh[tn], acc[tm][tn], 0, 0, 0);
                    acc[tm][tn] = __builtin_amdgcn_mfma_f32_16x16x32_bf16(al[tm], bh[tn], acc[tm][tn], 0, 0, 0);
                    acc[tm][tn] = __builtin_amdgcn_mfma_f32_16x16x32_bf16(ah[tm], bl[tn], acc[tm][tn], 0, 0, 0);
                }
        }
    }

    const int slice = nt*2 + wn;          // 0..23
    const int g  = slice / 6;
    const int jj = slice % 6;
    const int b  = mt >> 5;

    // ---- RoPE in C-fragment space (Q and K): dims cl (tn=0) & 16+cl (tn=1)
    if (jj != 5) {
        #pragma unroll
        for (int tm = 0; tm < 2; ++tm)
            #pragma unroll
            for (int r = 0; r < 4; ++r) {
                int m = mt*64 + wm*32 + 16*tm + 4*qd + r;
                int t = m & 2047;
                float c1 = cosp[t*ROPEN + cl],      s1 = sinp[t*ROPEN + cl];
                float c2 = cosp[t*ROPEN + 16 + cl], s2 = sinp[t*ROPEN + 16 + cl];
                float x1 = acc[tm][0][r], x2 = acc[tm][1][r];
                acc[tm][0][r] = x1*c1 - x2*s1;
                acc[tm][1][r] = x2*c2 + x1*s2;
            }
    }

    if (jj < 4) {
        #pragma unroll
        for (int tm = 0; tm < 2; ++tm)
            #pragma unroll
            for (int tn = 0; tn < 4; ++tn)
                #pragma unroll
                for (int r = 0; r < 4; ++r) {
                    int m = mt*64 + wm*32 + 16*tm + 4*qd + r;
                    Qf[(size_t)m*1024 + (g*4 + jj)*64 + 16*tn + cl] = acc[tm][tn][r];
                }
    } else {
        // K/V: per-slice shared 64x67 transpose buffer (both wm waves fill it)
        float* Lw = (float*)(smem + wn*17152);   // 64 x 67 f32 = 17152 B
        __syncthreads();   // main-loop LDS reads complete (uniform: KV block)
        #pragma unroll
        for (int tm = 0; tm < 2; ++tm)
            #pragma unroll
            for (int tn = 0; tn < 4; ++tn)
                #pragma unroll
                for (int r = 0; r < 4; ++r)
                    Lw[(wm*32 + 16*tm + 4*qd + r)*67 + 16*tn + cl] = acc[tm][tn][r];
        __syncthreads();

        const int cloc = mt & 31;                // 64-key tile index within b
        ushort* img = ((jj == 4) ? Kimg : Vimg)
                      + (size_t)(b*4 + g)*262144 + (size_t)cloc*8192;
        if (jj == 4) {
            // wave wm writes rows [32wm,32wm+32); lane-halves split chunks
            const int rr = wm*32 + (lane & 31);
            const int cb = (lane >> 5) * 4;
            float f[8];
            #pragma unroll
            for (int cc = 0; cc < 4; ++cc) {
                const int ch = cb + cc;
                *(float4*)f       = *(const float4*)(&Lw[rr*67 + ch*8]);
                *(float4*)(f + 4) = *(const float4*)(&Lw[rr*67 + ch*8 + 4]);
                uint4 h4, l4;
                split_pack8(f, h4, l4);
                int phys = ch ^ (rr & 7);
                *(uint4*)(img + rr*64 + phys*8)        = h4;
                *(uint4*)(img + 4096 + rr*64 + phys*8) = l4;
            }
        } else {
            // wave wm writes chunks [4wm,4wm+4) (rows it owns), all 64 dims
            const int d = lane;
            float f[8];
            #pragma unroll
            for (int cc = 0; cc < 4; ++cc) {
                const int ch = wm*4 + cc;
                #pragma unroll
                for (int i = 0; i < 8; ++i) f[i] = Lw[(ch*8 + i)*67 + d];
                uint4 h4;
                rtn_pack8(f, h4);
                int phys = ch ^ (d & 7);
                *(uint4*)(img + d*64 + phys*8) = h4;   // hi only
            }
        }
    }
}

// ---- output projection: out = yb @ Wout, 64M x 128N tiles ----
__global__ __launch_bounds__(256, 2) void gemm_out_mfma(const char* __restrict__ Aimg,
                                                        const char* __restrict__ Bimg,
                                                        float* __restrict__ C) {
    __shared__ __align__(16) char smem[49152];
    const int tid = threadIdx.x;
    const int nt = blockIdx.x, mt = blockIdx.y;   // mt: 64-row tile (0..63)

    const int wv = tid >> 6;
    const int wm = wv & 1, wn = wv >> 1;
    const int lane = tid & 63;
    const int qd = lane >> 4, cl = lane & 15;
    const int wslot = (tid & 192) * 16;

    floatx4 acc[2][4];
    #pragma unroll
    for (int tm = 0; tm < 2; ++tm)
        #pragma unroll
        for (int tn = 0; tn < 4; ++tn)
            acc[tm][tn] = (floatx4){0.f, 0.f, 0.f, 0.f};

    for (int c = 0; c < 16; ++c) {
        __syncthreads();
        {
            const char* sA = Aimg + ((size_t)((mt >> 1)*16 + c))*32768
                                  + (mt & 1)*8192 + (size_t)tid*16;
            const char* sB = Bimg + ((size_t)(nt*16 + c))*32768 + (size_t)tid*16;
            lds_async16(smem + wslot,          sA);
            lds_async16(smem + 4096  + wslot,  sA + 4096);
            lds_async16(smem + 8192  + wslot,  sA + 16384);
            lds_async16(smem + 12288 + wslot,  sA + 16384 + 4096);
            #pragma unroll
            for (int j = 0; j < 4; ++j) {
                lds_async16(smem + 16384 + j*4096 + wslot, sB + j*4096);
                lds_async16(smem + 32768 + j*4096 + wslot, sB + 16384 + j*4096);
            }
        }
        __syncthreads();

        #pragma unroll
        for (int s = 0; s < 2; ++s) {
            const int phys = ((s*4 + qd) ^ (cl & 7)) * 16;
            short8 ah[2], al[2], bh[4], bl[4];
            #pragma unroll
            for (int tt = 0; tt < 2; ++tt) {
                const int rA = wm*32 + 16*tt + cl;
                ah[tt] = *(const short8*)(smem + rA*128 + phys);
                al[tt] = *(const short8*)(smem + 8192 + rA*128 + phys);
            }
            #pragma unroll
            for (int tt = 0; tt < 4; ++tt) {
                const int rB = wn*64 + 16*tt + cl;
                bh[tt] = *(const short8*)(smem + 16384 + rB*128 + phys);
                bl[tt] = *(const short8*)(smem + 32768 + rB*128 + phys);
            }
            #pragma unroll
            for (int tm = 0; tm < 2; ++tm)
                #pragma unroll
                for (int tn = 0; tn < 4; ++tn) {
                    acc[tm][tn] = __builtin_amdgcn_mfma_f32_16x16x32_bf16(ah[tm], bh[tn], acc[tm][tn], 0, 0, 0);
                    acc[tm][tn] = __builtin_amdgcn_mfma_f32_16x16x32_bf16(al[tm], bh[tn], acc[tm][tn], 0, 0, 0);
                    acc[tm][tn] = __builtin_amdgcn_mfma_f32_16x16x32_bf16(ah[tm], bl[tn], acc[tm][tn], 0, 0, 0);
                }
        }
    }

    #pragma unroll
    for (int tm = 0; tm < 2; ++tm)
        #pragma unroll
        for (int tn = 0; tn < 4; ++tn)
            #pragma unroll
            for (int r = 0; r < 4; ++r) {
                int m = mt*64 + wm*32 + 16*tm + 4*qd + r;
                int n = nt*128 + wn*64 + 16*tn + cl;
                C[(size_t)m*1024 + n] = acc[tm][tn][r];
            }
}

// ---------------------------------------------------------------------------
// MFMA flash attention v9.  Same decomposition as v8 (64 q-rows/block, 32-key
// tiles, 1024 blocks = 4/CU), but on a VALU diet: v8's counters showed
// VALUBusy ~= MfmaUtil ~= 30% -> VALU co-limiting.  Changes:
//  - all K ds_read offsets hoisted to 2 lane-constant bases; tt/hi-lo/buf
//    become immediate offsets (loop unrolled by 2 so buf is a literal)
//  - V global offsets hoisted to 8 lane-constant 32-bit offsets + uniform
//    base pointer stepping by 16384 (saddr-form loads)
//  - P LDS store/load addresses hoisted to single bases + immediates
//  - log2(e)/8 folded into the Q pre-scale -> exp2f (saves 8 v_mul/iter)
// ---------------------------------------------------------------------------
__global__ __launch_bounds__(256, 4) void attn9(const float* __restrict__ Qf,
                                                const char* __restrict__ Kimg,
                                                const char* __restrict__ Vimg,
                                                char* __restrict__ Yimg) {
    __shared__ __align__(16) char smem[20992];
    ushort* Pp = (ushort*)(smem + 16384);    // 64 rows x stride 36 ushorts

    const int tid  = threadIdx.x;
    const int wv   = tid >> 6;
    const int lane = tid & 63;
    const int qd   = lane >> 4;
    const int cl   = lane & 15;

    const int bg    = blockIdx.x & 7;        // XCD-aligned
    const int inner = blockIdx.x >> 3;
    const int hj    = inner >> 5;            // head within group (0..3)
    const int qt    = inner & 31;            // 64-row q tile (0..31)
    const int b = bg >> 2, g = bg & 3;
    const int h = g*4 + hj;

    // ---- Q fragments -> registers, pre-scaled by log2(e)/8 ----
    short8 qh[2], ql[2];
    {
        const float* qp = Qf + (size_t)(b*2048 + qt*64 + wv*16 + cl)*1024
                             + h*64 + 8*qd;
        #pragma unroll
        for (int s = 0; s < 2; ++s) {
            float f[8];
            *(float4*)f       = *(const float4*)(qp + 32*s);
            *(float4*)(f + 4) = *(const float4*)(qp + 32*s + 4);
            #pragma unroll
            for (int i = 0; i < 8; ++i) f[i] *= 0.125f * 1.44269504088896f;
            uint4 h4, l4;
            split_pack8(f, h4, l4);
            qh[s] = __builtin_bit_cast(short8, h4);
            ql[s] = __builtin_bit_cast(short8, l4);
        }
    }

    floatx4 accO[4] = {};
    float lsum[4] = {};

    const char* Kg0 = Kimg + (size_t)bg*524288;
    const char* Vg0 = Vimg + (size_t)bg*524288;
    const int wslot = (tid & 192) * 16;      // wave-uniform LDS byte offset

    // lane-constant offsets (loop-invariant)
    int kb[2];                               // K LDS frag base, per s
    #pragma unroll
    for (int s = 0; s < 2; ++s)
        kb[s] = cl*128 + (((4*s + qd) ^ (cl & 7)) * 16);
    int voff[2][4];                          // V global offset, per parity/tt
    #pragma unroll
    for (int par = 0; par < 2; ++par)
        #pragma unroll
        for (int tt = 0; tt < 4; ++tt)
            voff[par][tt] = (16*tt + cl)*128 + (((par*4 + qd) ^ (cl & 7)) * 16);
    const int pst = (16*wv + 4*qd)*36 + cl;  // P store base (ushort idx)
    const int pld = (16*wv + cl)*36 + 8*qd;  // P load base

    // stage K 32-key half-tile 0 into buf 0 (hi 4K + lo 4K)
    {
        const char* src = Kg0 + (size_t)tid*16;
        lds_async16(smem + wslot,        src);
        lds_async16(smem + 4096 + wslot, src + 8192);
    }

    #pragma unroll 2
    for (int c = 0; c < TSEQ/32; ++c) {
        __syncthreads();   // publishes K tile c (drains vmcnt); reads of c-1 done
        const int buf = c & 1;
        if (c + 1 < TSEQ/32) {
            const char* src = Kg0 + (size_t)((c+1) >> 1)*16384
                                  + ((c+1) & 1)*4096 + (size_t)tid*16;
            lds_async16(smem + ((c+1) & 1)*8192 + wslot,        src);
            lds_async16(smem + ((c+1) & 1)*8192 + 4096 + wslot, src + 8192);
        }
        const char* Kl = smem + buf*8192;

        // ---- S = Q.K^T (3-pass split; result in log2 units) ----
        floatx4 accS[2] = {};
        __builtin_amdgcn_s_setprio(1);
        #pragma unroll
        for (int s = 0; s < 2; ++s) {
            #pragma unroll
            for (int tt = 0; tt < 2; ++tt) {
                short8 bh = *(const short8*)(Kl + kb[s] + tt*2048);
                short8 bl = *(const short8*)(Kl + kb[s] + tt*2048 + 4096);
                accS[tt] = __builtin_amdgcn_mfma_f32_16x16x32_bf16(qh[s], bh, accS[tt], 0, 0, 0);
                accS[tt] = __builtin_amdgcn_mfma_f32_16x16x32_bf16(ql[s], bh, accS[tt], 0, 0, 0);
                accS[tt] = __builtin_amdgcn_mfma_f32_16x16x32_bf16(qh[s], bl, accS[tt], 0, 0, 0);
            }
        }
        __builtin_amdgcn_s_setprio(0);

        // ---- softmax: exp2, P as RTN bf16 (wave-private rows, no barrier) ----
        #pragma unroll
        for (int r = 0; r < 4; ++r) {
            float p0 = exp2f(accS[0][r]);
            float p1 = exp2f(accS[1][r]);
            lsum[r] += p0 + p1;
            Pp[pst + r*36]      = bf16_rtn(p0);
            Pp[pst + r*36 + 16] = bf16_rtn(p1);
        }

        // ---- O += P.V : V direct from image (L2-resident; saddr loads) ----
        const char* Vg = Vg0 + (size_t)(c >> 1)*16384;
        short8 pa = *(const short8*)(Pp + pld);
        __builtin_amdgcn_s_setprio(1);
        #pragma unroll
        for (int tt = 0; tt < 4; ++tt) {
            short8 vh = *(const short8*)(Vg + voff[buf][tt]);
            accO[tt] = __builtin_amdgcn_mfma_f32_16x16x32_bf16(pa, vh, accO[tt], 0, 0, 0);
        }
        __builtin_amdgcn_s_setprio(0);
    }

    // ---- epilogue: normalize, transpose via LDS, write split y A-image ----
    __syncthreads();                 // all waves done with K/P buffers
    float* Lt = (float*)smem;        // 64 rows x 66 f32 = 16896 B
    #pragma unroll
    for (int r = 0; r < 4; ++r) {
        float l = lsum[r];
        l += __shfl_xor(l, 1);
        l += __shfl_xor(l, 2);
        l += __shfl_xor(l, 4);
        l += __shfl_xor(l, 8);
        float inv = 1.0f / l;
        int row = 16*wv + 4*qd + r;
        Lt[row*66 + cl]      = accO[0][r] * inv;
        Lt[row*66 + 16 + cl] = accO[1][r] * inv;
        Lt[row*66 + 32 + cl] = accO[2][r] * inv;
        Lt[row*66 + 48 + cl] = accO[3][r] * inv;
    }
    __syncthreads();
    {
        const int r0 = tid >> 2;     // 0..63
        const int qq = tid & 3;      // 16-col quarter
        float f[16];
        #pragma unroll
        for (int u = 0; u < 8; ++u)
            *(float2*)(f + 2*u) = *(const float2*)(&Lt[r0*66 + qq*16 + 2*u]);
        const int R = (qt & 1)*64 + r0;              // row within 128-row Y tile
        char* tile = Yimg + (size_t)((b*16 + (qt >> 1))*16 + h) * 32768;
        #pragma unroll
        for (int cc = 0; cc < 2; ++cc) {
            uint4 h4, l4;
            split_pack8(f + 8*cc, h4, l4);
            int j    = qq*2 + cc;
            int phys = j ^ (R & 7);
            *(uint4*)(tile + R*128 + phys*16)         = h4;
            *(uint4*)(tile + 16384 + R*128 + phys*16) = l4;
        }
    }
}

// ---------------------------------------------------------------------------
extern "C" void kernel_launch(void* const* d_in, const int* in_sizes, int n_in,
                              void* d_out, int out_size, void* d_ws, size_t ws_size,
                              hipStream_t stream) {
    const float* x    = (const float*)d_in[0];
    const float* cosp = (const float*)d_in[1];
    const float* sinp = (const float*)d_in[2];
    // d_in[3] = mask: unused by the reference computation
    const float* Wqkv = (const float*)d_in[4];
    const float* Wout = (const float*)d_in[5];
    float* out = (float*)d_out;

    char* ws = (char*)d_ws;
    float*  Qf    = (float*)(ws);                      // [ 0,16M)
    ushort* Kimg  = (ushort*)(ws + ((size_t)16<<20));  // [16,20M)
    ushort* Vimg  = (ushort*)(ws + ((size_t)20<<20));  // [20,24M)
    char*   Bo    = ws + ((size_t)24<<20);             // [24,28M)
    char*   Ximg  = ws + ((size_t)28<<20);             // [28,44M)  (dead after qkv-gemm)
    char*   Bq    = ws + ((size_t)44<<20);             // [44,50M)
    char*   Yimg  = ws + ((size_t)28<<20);             // [28,44M)  (over dead Ximg)

    // 1) input + weight images
    conv_xy<<<512, 256, 0, stream>>>(x, Ximg);
    conv_w<<<dim3(16, 12), 256, 0, stream>>>(Wqkv, FQKV, Bq);
    conv_w<<<dim3(16, 8), 256, 0, stream>>>(Wout, DEMBED, Bo);
    // 2) qkv projection + fused RoPE + K/V image build (768 blocks = 3/CU)
    gemm_qkv_mfma<<<dim3(12, 64), 256, 0, stream>>>(Ximg, Bq, cosp, sinp,
                                                    Qf, Kimg, Vimg);
    // 3) attention -> writes y's A-image directly (1024 blocks = 4/CU)
    attn9<<<1024, 256, 0, stream>>>(Qf, (const char*)Kimg, (const char*)Vimg,
                                    Yimg);
    // 4) out = y @ Wout
    gemm_out_mfma<<<dim3(8, 64), 256, 0, stream>>>(Yimg, Bo, out);
}

// Round 4
// 241.019 us; speedup vs baseline: 1.1243x; 1.1243x over previous
//
#include <hip/hip_runtime.h>
#include <hip/hip_bf16.h>
#include <math.h>

// Problem constants (fixed shapes)
#define BATCH   2
#define TSEQ    2048
#define DEMBED  1024
#define NHEAD   16
#define DHEAD   64
#define NGROUP  4
#define ROPEN   32
#define FQKV    1536          // (16 + 2*4) * 64
#define MROWS   (BATCH*TSEQ)  // 4096

typedef __attribute__((ext_vector_type(8))) short short8;   // 8 bf16 = 4 VGPR
typedef __attribute__((ext_vector_type(4))) float floatx4;  // MFMA C/D

// ---------------------------------------------------------------------------
// split helpers: f = hi + lo, hi = truncate-to-bf16(f), lo = bf16(f - hi).
// ---------------------------------------------------------------------------
__device__ __forceinline__ void split_pack8(const float* f, uint4& h4, uint4& l4) {
    uint u[8], lu[8];
    #pragma unroll
    for (int j = 0; j < 8; ++j) {
        u[j] = __float_as_uint(f[j]);
        float lf = f[j] - __uint_as_float(u[j] & 0xffff0000u);
        lu[j] = __float_as_uint(lf);
    }
    h4.x = __builtin_amdgcn_perm(u[1], u[0], 0x07060302u);
    h4.y = __builtin_amdgcn_perm(u[3], u[2], 0x07060302u);
    h4.z = __builtin_amdgcn_perm(u[5], u[4], 0x07060302u);
    h4.w = __builtin_amdgcn_perm(u[7], u[6], 0x07060302u);
    l4.x = __builtin_amdgcn_perm(lu[1], lu[0], 0x07060302u);
    l4.y = __builtin_amdgcn_perm(lu[3], lu[2], 0x07060302u);
    l4.z = __builtin_amdgcn_perm(lu[5], lu[4], 0x07060302u);
    l4.w = __builtin_amdgcn_perm(lu[7], lu[6], 0x07060302u);
}

// round-to-nearest bf16 pack of 8 floats -> hi-only uint4 (unbiased)
__device__ __forceinline__ void rtn_pack8(const float* f, uint4& h4) {
    uint t[8];
    #pragma unroll
    for (int j = 0; j < 8; ++j)
        t[j] = __float_as_uint(f[j]) + 0x8000u;
    h4.x = __builtin_amdgcn_perm(t[1], t[0], 0x07060302u);
    h4.y = __builtin_amdgcn_perm(t[3], t[2], 0x07060302u);
    h4.z = __builtin_amdgcn_perm(t[5], t[4], 0x07060302u);
    h4.w = __builtin_amdgcn_perm(t[7], t[6], 0x07060302u);
}

// pack two floats -> one u32 of two RTN bf16 (lo = f0, hi = f1)
__device__ __forceinline__ uint pk_bf16x2(float f0, float f1) {
    uint u0 = __float_as_uint(f0) + 0x8000u;
    uint u1 = __float_as_uint(f1) + 0x8000u;
    return __builtin_amdgcn_perm(u1, u0, 0x07060302u);
}

// native 2^x (single VOP1; log2 scaling folded into operands upstream)
__device__ __forceinline__ float fast_exp2(float x) {
    float r;
    asm("v_exp_f32 %0, %1" : "=v"(r) : "v"(x));
    return r;
}

// async 16B/lane global->LDS copy; lds must be wave-uniform (HW adds lane*16)
__device__ __forceinline__ void lds_async16(void* lds, const void* gp) {
    __builtin_amdgcn_global_load_lds(
        (const __attribute__((address_space(1))) unsigned int*)gp,
        (__attribute__((address_space(3))) unsigned int*)lds,
        16, 0, 0);
}

// ===========================================================================
// MFMA-GEMM: pre-swizzled hi/lo bf16 images.
// Image layout (A and B^T): per (tile128, kblock64):
//   [hi: 128 rows x 128B][lo: 128 rows x 128B] = 32 KB, tile index = rt*16 + c.
//   Row r holds 64 bf16 k-values as 8 chunks of 16B; chunk j at phys j^(r&7).
// ===========================================================================

// ---- x converter: [4096][1024] f32 row-major -> A-image ----
__global__ __launch_bounds__(256) void conv_xy(const float* __restrict__ in,
                                               char* __restrict__ img) {
    const int tid = threadIdx.x;
    const int c   = blockIdx.x & 15;
    const int mt  = blockIdx.x >> 4;
    const int r    = tid >> 1;
    const int half = tid & 1;

    const float* src = in + (size_t)(mt*128 + r)*1024 + c*64 + half*32;
    float f[32];
    #pragma unroll
    for (int u = 0; u < 8; ++u)
        *(float4*)(f + 4*u) = *(const float4*)(src + 4*u);

    char* tile = img + ((size_t)(mt*16 + c)) * 32768;
    #pragma unroll
    for (int cc = 0; cc < 4; ++cc) {
        uint4 h4, l4;
        split_pack8(f + cc*8, h4, l4);
        int j    = half*4 + cc;
        int phys = j ^ (r & 7);
        *(uint4*)(tile + r*128 + phys*16)         = h4;
        *(uint4*)(tile + 16384 + r*128 + phys*16) = l4;
    }
}

// ---- weight converter (transpose): W [1024][N] f32 -> B^T image ----
__global__ __launch_bounds__(256) void conv_w(const float* __restrict__ W,
                                              int N,
                                              char* __restrict__ img) {
    __shared__ float Lf[64][132];
    const int tid = threadIdx.x;
    const int c   = blockIdx.x;
    const int nt  = blockIdx.y;

    {
        const int kk = tid >> 2;
        const int nc = (tid & 3) * 32;
        const float* src = W + (size_t)(c*64 + kk)*N + nt*128 + nc;
        #pragma unroll
        for (int u = 0; u < 8; ++u)
            *(float4*)(&Lf[kk][nc + 4*u]) = *(const float4*)(src + 4*u);
    }
    __syncthreads();

    char* tile = img + ((size_t)(nt*16 + c)) * 32768;
    #pragma unroll
    for (int rep = 0; rep < 4; ++rep) {
        int idx = rep*256 + tid;
        int n = idx & 127;
        int j = idx >> 7;
        float v[8];
        #pragma unroll
        for (int i = 0; i < 8; ++i) v[i] = Lf[j*8 + i][n];
        uint4 h4, l4;
        split_pack8(v, h4, l4);
        int phys = j ^ (n & 7);
        *(uint4*)(tile + n*128 + phys*16)         = h4;
        *(uint4*)(tile + 16384 + n*128 + phys*16) = l4;
    }
}

// ---- split-bf16 MFMA GEMM core: 128x128 tile, BK=64, 4 waves (2x2) ----
struct GemmAcc { floatx4 a[4][4]; };

__device__ __forceinline__ void gemm_mfma_core(const char* __restrict__ Aimg,
                                               const char* __restrict__ Bimg,
                                               char* smem, int mt, int nt,
                                               int tid, GemmAcc& G) {
    const int wv = tid >> 6;
    const int wm = wv & 1, wn = wv >> 1;
    const int lane = tid & 63;
    const int qd = lane >> 4, cl = lane & 15;
    const int wslot = (tid & 192) * 16;     // wave-uniform LDS byte offset

    #pragma unroll
    for (int tm = 0; tm < 4; ++tm)
        #pragma unroll
        for (int tn = 0; tn < 4; ++tn)
            G.a[tm][tn] = (floatx4){0.f, 0.f, 0.f, 0.f};

    for (int c = 0; c < 16; ++c) {
        __syncthreads();                    // prev-iter LDS reads complete
        {
            const uint4* gA = (const uint4*)(Aimg + ((size_t)(mt*16 + c)) * 32768) + tid;
            const uint4* gB = (const uint4*)(Bimg + ((size_t)(nt*16 + c)) * 32768) + tid;
            #pragma unroll
            for (int j = 0; j < 8; ++j) {
                lds_async16(smem + j*4096 + wslot,         gA + j*256);
                lds_async16(smem + 32768 + j*4096 + wslot, gB + j*256);
            }
        }
        __syncthreads();                    // vmcnt(0) drain publishes tile

        #pragma unroll
        for (int s = 0; s < 2; ++s) {
            const int phys = ((s*4 + qd) ^ (cl & 7)) * 16;
            short8 ah[4], al[4], bh[4], bl[4];
            #pragma unroll
            for (int tt = 0; tt < 4; ++tt) {
                const int rA = wm*64 + 16*tt + cl;
                ah[tt] = *(const short8*)(smem + rA*128 + phys);
                al[tt] = *(const short8*)(smem + 16384 + rA*128 + phys);
                const int rB = wn*64 + 16*tt + cl;
                bh[tt] = *(const short8*)(smem + 32768 + rB*128 + phys);
                bl[tt] = *(const short8*)(smem + 49152 + rB*128 + phys);
            }
            #pragma unroll
            for (int tm = 0; tm < 4; ++tm)
                #pragma unroll
                for (int tn = 0; tn < 4; ++tn) {
                    G.a[tm][tn] = __builtin_amdgcn_mfma_f32_16x16x32_bf16(ah[tm], bh[tn], G.a[tm][tn], 0, 0, 0);
                    G.a[tm][tn] = __builtin_amdgcn_mfma_f32_16x16x32_bf16(al[tm], bh[tn], G.a[tm][tn], 0, 0, 0);
                    G.a[tm][tn] = __builtin_amdgcn_mfma_f32_16x16x32_bf16(ah[tm], bl[tn], G.a[tm][tn], 0, 0, 0);
                }
        }
    }
}

// ---- qkv projection with fused RoPE + K/V image epilogue (round-2 config) --
__global__ __launch_bounds__(256, 2) void gemm_qkv_mfma(const char* __restrict__ Aimg,
                                                        const char* __restrict__ Bimg,
                                                        const float* __restrict__ cosp,
                                                        const float* __restrict__ sinp,
                                                        float* __restrict__ Qf,
                                                        ushort* __restrict__ Kimg,
                                                        ushort* __restrict__ Vimg) {
    __shared__ __align__(16) char smem[68608];   // main loop uses [0,65536)
    const int tid = threadIdx.x;
    const int nt = blockIdx.x, mt = blockIdx.y;

    GemmAcc G;
    gemm_mfma_core(Aimg, Bimg, smem, mt, nt, tid, G);

    const int wv = tid >> 6;
    const int wm = wv & 1, wn = wv >> 1;
    const int lane = tid & 63;
    const int qd = lane >> 4, cl = lane & 15;

    const int slice = nt*2 + wn;          // 0..23
    const int g  = slice / 6;
    const int jj = slice % 6;
    const int b  = mt >> 4;

    // ---- RoPE in C-fragment space (Q and K): dims cl (tn=0) & 16+cl (tn=1)
    if (jj != 5) {
        #pragma unroll
        for (int tm = 0; tm < 4; ++tm)
            #pragma unroll
            for (int r = 0; r < 4; ++r) {
                int m = mt*128 + wm*64 + 16*tm + 4*qd + r;
                int t = m & 2047;
                float c1 = cosp[t*ROPEN + cl],      s1 = sinp[t*ROPEN + cl];
                float c2 = cosp[t*ROPEN + 16 + cl], s2 = sinp[t*ROPEN + 16 + cl];
                float x1 = G.a[tm][0][r], x2 = G.a[tm][1][r];
                G.a[tm][0][r] = x1*c1 - x2*s1;
                G.a[tm][1][r] = x2*c2 + x1*s2;
            }
    }

    if (jj < 4) {
        #pragma unroll
        for (int tm = 0; tm < 4; ++tm)
            #pragma unroll
            for (int tn = 0; tn < 4; ++tn)
                #pragma unroll
                for (int r = 0; r < 4; ++r) {
                    int m = mt*128 + wm*64 + 16*tm + 4*qd + r;
                    Qf[(size_t)m*1024 + (g*4 + jj)*64 + 16*tn + cl] = G.a[tm][tn][r];
                }
    } else {
        // K/V: wave-private LDS transpose -> swizzled image
        // K: exact hi/lo split (truncate).  V: RTN hi only (attn uses hi only).
        float* Lw = (float*)(smem + wv*17152);   // 64 x 67 f32
        __syncthreads();   // main-loop LDS reads complete (uniform: KV block)
        #pragma unroll
        for (int tm = 0; tm < 4; ++tm)
            #pragma unroll
            for (int tn = 0; tn < 4; ++tn)
                #pragma unroll
                for (int r = 0; r < 4; ++r)
                    Lw[(16*tm + 4*qd + r)*67 + 16*tn + cl] = G.a[tm][tn][r];
        __syncthreads();

        const int cloc = (mt & 15)*2 + wm;       // 64-key tile index within b
        ushort* img = ((jj == 4) ? Kimg : Vimg)
                      + (size_t)(b*4 + g)*262144 + (size_t)cloc*8192;
        if (jj == 4) {
            const int rr = lane;
            float f[8];
            #pragma unroll
            for (int ch = 0; ch < 8; ++ch) {
                *(float4*)f       = *(const float4*)(&Lw[rr*67 + ch*8]);
                *(float4*)(f + 4) = *(const float4*)(&Lw[rr*67 + ch*8 + 4]);
                uint4 h4, l4;
                split_pack8(f, h4, l4);
                int phys = ch ^ (rr & 7);
                *(uint4*)(img + rr*64 + phys*8)        = h4;
                *(uint4*)(img + 4096 + rr*64 + phys*8) = l4;
            }
        } else {
            const int d = lane;
            float f[8];
            #pragma unroll
            for (int ch = 0; ch < 8; ++ch) {
                #pragma unroll
                for (int i = 0; i < 8; ++i) f[i] = Lw[(ch*8 + i)*67 + d];
                uint4 h4;
                rtn_pack8(f, h4);
                int phys = ch ^ (d & 7);
                *(uint4*)(img + d*64 + phys*8) = h4;   // hi only
            }
        }
    }
}

// ---- output projection: out = yb @ Wout, 64M x 128N tiles ----
__global__ __launch_bounds__(256, 2) void gemm_out_mfma(const char* __restrict__ Aimg,
                                                        const char* __restrict__ Bimg,
                                                        float* __restrict__ C) {
    __shared__ __align__(16) char smem[49152];
    const int tid = threadIdx.x;
    const int nt = blockIdx.x, mt = blockIdx.y;   // mt: 64-row tile (0..63)

    const int wv = tid >> 6;
    const int wm = wv & 1, wn = wv >> 1;
    const int lane = tid & 63;
    const int qd = lane >> 4, cl = lane & 15;
    const int wslot = (tid & 192) * 16;

    floatx4 acc[2][4];
    #pragma unroll
    for (int tm = 0; tm < 2; ++tm)
        #pragma unroll
        for (int tn = 0; tn < 4; ++tn)
            acc[tm][tn] = (floatx4){0.f, 0.f, 0.f, 0.f};

    for (int c = 0; c < 16; ++c) {
        __syncthreads();
        {
            const char* sA = Aimg + ((size_t)((mt >> 1)*16 + c))*32768
                                  + (mt & 1)*8192 + (size_t)tid*16;
            const char* sB = Bimg + ((size_t)(nt*16 + c))*32768 + (size_t)tid*16;
            lds_async16(smem + wslot,          sA);
            lds_async16(smem + 4096  + wslot,  sA + 4096);
            lds_async16(smem + 8192  + wslot,  sA + 16384);
            lds_async16(smem + 12288 + wslot,  sA + 16384 + 4096);
            #pragma unroll
            for (int j = 0; j < 4; ++j) {
                lds_async16(smem + 16384 + j*4096 + wslot, sB + j*4096);
                lds_async16(smem + 32768 + j*4096 + wslot, sB + 16384 + j*4096);
            }
        }
        __syncthreads();

        #pragma unroll
        for (int s = 0; s < 2; ++s) {
            const int phys = ((s*4 + qd) ^ (cl & 7)) * 16;
            short8 ah[2], al[2], bh[4], bl[4];
            #pragma unroll
            for (int tt = 0; tt < 2; ++tt) {
                const int rA = wm*32 + 16*tt + cl;
                ah[tt] = *(const short8*)(smem + rA*128 + phys);
                al[tt] = *(const short8*)(smem + 8192 + rA*128 + phys);
            }
            #pragma unroll
            for (int tt = 0; tt < 4; ++tt) {
                const int rB = wn*64 + 16*tt + cl;
                bh[tt] = *(const short8*)(smem + 16384 + rB*128 + phys);
                bl[tt] = *(const short8*)(smem + 32768 + rB*128 + phys);
            }
            #pragma unroll
            for (int tm = 0; tm < 2; ++tm)
                #pragma unroll
                for (int tn = 0; tn < 4; ++tn) {
                    acc[tm][tn] = __builtin_amdgcn_mfma_f32_16x16x32_bf16(ah[tm], bh[tn], acc[tm][tn], 0, 0, 0);
                    acc[tm][tn] = __builtin_amdgcn_mfma_f32_16x16x32_bf16(al[tm], bh[tn], acc[tm][tn], 0, 0, 0);
                    acc[tm][tn] = __builtin_amdgcn_mfma_f32_16x16x32_bf16(ah[tm], bl[tn], acc[tm][tn], 0, 0, 0);
                }
        }
    }

    #pragma unroll
    for (int tm = 0; tm < 2; ++tm)
        #pragma unroll
        for (int tn = 0; tn < 4; ++tn)
            #pragma unroll
            for (int r = 0; r < 4; ++r) {
                int m = mt*64 + wm*32 + 16*tm + 4*qd + r;
                int n = nt*128 + wn*64 + 16*tn + cl;
                C[(size_t)m*1024 + n] = acc[tm][tn][r];
            }
}

// ---------------------------------------------------------------------------
// MFMA flash attention v10.  attn8 base (64 q-rows/block, 1024 blocks = 4/CU)
// with two changes:
//  (1) 64-key staged K tiles (dbuf 32K) with ONE barrier per 64 keys; two
//      32-key compute sub-rounds per staged tile.  Halves the barrier-convoy
//      and prefetch overhead; the vmcnt drain at the barrier covers loads
//      issued a full 64-key compute earlier.
//  (2) swapped-operand S and PV: S^T = mfma(K, Q) (identical regs/addresses,
//      A/B fragment lane-layouts are the same; only the argument order
//      swaps).  Each lane then holds a q-column slice of S^T: exp in-place
//      (native v_exp_f32; log2e folded into the Q pre-scale), P packed
//      pairwise to bf16x2 u32s (3 ops/u32) and stored with 2 ds_write_b64
//      (was 8 ds_write_b16 + per-element rtn), lsum is one scalar reduced by
//      2 shfl at the end (was 4 x 4 shfl), PV = mfma(V, P) with the same V
//      image addresses as before.
// LDS: K dbuf 32K | P 64 rows x 20 u32 = 5K -> 37888 B, 4 blocks/CU.
// ---------------------------------------------------------------------------
__global__ __launch_bounds__(256, 4) void attn10(const float* __restrict__ Qf,
                                                 const char* __restrict__ Kimg,
                                                 const char* __restrict__ Vimg,
                                                 char* __restrict__ Yimg) {
    __shared__ __align__(16) char smem[37888];
    uint* Pp32 = (uint*)(smem + 32768);      // 64 rows x stride 20 u32

    const int tid  = threadIdx.x;
    const int wv   = tid >> 6;
    const int lane = tid & 63;
    const int qd   = lane >> 4;
    const int cl   = lane & 15;

    const int bg    = blockIdx.x & 7;        // XCD-aligned
    const int inner = blockIdx.x >> 3;
    const int hj    = inner >> 5;            // head within group (0..3)
    const int qt    = inner & 31;            // 64-row q tile (0..31)
    const int b = bg >> 2, g = bg & 3;
    const int h = g*4 + hj;

    // ---- Q fragments -> registers, pre-scaled by log2(e)/8 ----
    // (S then comes out in log2 units; exp = single v_exp_f32)
    short8 qh[2], ql[2];
    {
        const float* qp = Qf + (size_t)(b*2048 + qt*64 + wv*16 + cl)*1024
                             + h*64 + 8*qd;
        #pragma unroll
        for (int s = 0; s < 2; ++s) {
            float f[8];
            *(float4*)f       = *(const float4*)(qp + 32*s);
            *(float4*)(f + 4) = *(const float4*)(qp + 32*s + 4);
            #pragma unroll
            for (int i = 0; i < 8; ++i) f[i] *= 0.125f * 1.44269504088896f;
            uint4 h4, l4;
            split_pack8(f, h4, l4);
            qh[s] = __builtin_bit_cast(short8, h4);
            ql[s] = __builtin_bit_cast(short8, l4);
        }
    }

    floatx4 accOT[4] = {};                   // O^T: [d-block][d-sub], q = cl
    float lsum = 0.f;                        // partial softmax denom for q=cl

    const char* Kg0 = Kimg + (size_t)bg*524288;
    const char* Vg0 = Vimg + (size_t)bg*524288;
    const int wslot = (tid & 192) * 16;      // wave-uniform LDS byte offset

    // stage K 64-key tile 0 into buf 0 (hi 8K + lo 8K, image-linear)
    {
        const char* src = Kg0 + (size_t)tid*16;
        #pragma unroll
        for (int j = 0; j < 4; ++j)
            lds_async16(smem + j*4096 + wslot, src + j*4096);
    }

    for (int c = 0; c < TSEQ/64; ++c) {
        __syncthreads();   // publishes K tile c (drains vmcnt); reads of c-1 done
        const int buf = c & 1;
        if (c + 1 < TSEQ/64) {
            const char* src = Kg0 + (size_t)(c+1)*16384 + (size_t)tid*16;
            #pragma unroll
            for (int j = 0; j < 4; ++j)
                lds_async16(smem + (1-buf)*16384 + j*4096 + wslot, src + j*4096);
        }
        const char* Kl = smem + buf*16384;
        const char* Vg = Vg0 + (size_t)c*16384;

        #pragma unroll
        for (int hh = 0; hh < 2; ++hh) {     // 32-key sub-round
            // ---- S^T = K.Q^T (3-pass split; swapped operands) ----
            floatx4 accST[2] = {};
            __builtin_amdgcn_s_setprio(1);
            #pragma unroll
            for (int s = 0; s < 2; ++s) {
                #pragma unroll
                for (int tt = 0; tt < 2; ++tt) {
                    const int off = (32*hh + 16*tt + cl)*128
                                  + (((4*s + qd) ^ (cl & 7))*16);
                    short8 kh = *(const short8*)(Kl + off);
                    short8 kl = *(const short8*)(Kl + 8192 + off);
                    accST[tt] = __builtin_amdgcn_mfma_f32_16x16x32_bf16(kh, qh[s], accST[tt], 0, 0, 0);
                    accST[tt] = __builtin_amdgcn_mfma_f32_16x16x32_bf16(kh, ql[s], accST[tt], 0, 0, 0);
                    accST[tt] = __builtin_amdgcn_mfma_f32_16x16x32_bf16(kl, qh[s], accST[tt], 0, 0, 0);
                }
            }
            __builtin_amdgcn_s_setprio(0);

            // ---- softmax: exp2 (S already in log2 units), pack pairwise ----
            // lane (qd,cl): accST[tt][r] = S^T[key 16tt+4qd+r][q=16wv+cl]
            float p[8];
            #pragma unroll
            for (int tt = 0; tt < 2; ++tt)
                #pragma unroll
                for (int r = 0; r < 4; ++r)
                    p[4*tt + r] = fast_exp2(accST[tt][r]);
            lsum += ((p[0] + p[1]) + (p[2] + p[3]))
                  + ((p[4] + p[5]) + (p[6] + p[7]));
            {
                uint* prow = Pp32 + (16*wv + cl)*20 + 2*qd;
                uint2 w0; w0.x = pk_bf16x2(p[0], p[1]); w0.y = pk_bf16x2(p[2], p[3]);
                uint2 w1; w1.x = pk_bf16x2(p[4], p[5]); w1.y = pk_bf16x2(p[6], p[7]);
                *(uint2*)(prow)     = w0;    // keys 4qd..4qd+3
                *(uint2*)(prow + 8) = w1;    // keys 16+4qd..16+4qd+3
            }

            // ---- O^T += V.P : V direct from image (L2-resident) ----
            uint4 paw = *(const uint4*)(Pp32 + (16*wv + cl)*20 + 4*qd);
            short8 pa = __builtin_bit_cast(short8, paw);
            __builtin_amdgcn_s_setprio(1);
            #pragma unroll
            for (int tt = 0; tt < 4; ++tt) {
                const int off = (16*tt + cl)*128 + (((4*hh + qd) ^ (cl & 7))*16);
                short8 vh = *(const short8*)(Vg + off);
                accOT[tt] = __builtin_amdgcn_mfma_f32_16x16x32_bf16(vh, pa, accOT[tt], 0, 0, 0);
            }
            __builtin_amdgcn_s_setprio(0);
        }
    }

    // ---- epilogue: normalize, transpose via LDS, write split y A-image ----
    __syncthreads();                 // all waves done with K/P buffers
    float* Lt = (float*)smem;        // 64 rows x 66 f32 = 16896 B
    {
        float l = lsum;
        l += __shfl_xor(l, 16);
        l += __shfl_xor(l, 32);
        float inv = 1.0f / l;
        const int row = 16*wv + cl;  // q row
        #pragma unroll
        for (int tt = 0; tt < 4; ++tt)
            #pragma unroll
            for (int r = 0; r < 4; ++r)
                Lt[row*66 + 16*tt + 4*qd + r] = accOT[tt][r] * inv;
    }
    __syncthreads();
    {
        const int r0 = tid >> 2;     // 0..63
        const int qq = tid & 3;      // 16-col quarter
        float f[16];
        #pragma unroll
        for (int u = 0; u < 8; ++u)
            *(float2*)(f + 2*u) = *(const float2*)(&Lt[r0*66 + qq*16 + 2*u]);
        const int R = (qt & 1)*64 + r0;              // row within 128-row Y tile
        char* tile = Yimg + (size_t)((b*16 + (qt >> 1))*16 + h) * 32768;
        #pragma unroll
        for (int cc = 0; cc < 2; ++cc) {
            uint4 h4, l4;
            split_pack8(f + 8*cc, h4, l4);
            int j    = qq*2 + cc;
            int phys = j ^ (R & 7);
            *(uint4*)(tile + R*128 + phys*16)         = h4;
            *(uint4*)(tile + 16384 + R*128 + phys*16) = l4;
        }
    }
}

// ---------------------------------------------------------------------------
extern "C" void kernel_launch(void* const* d_in, const int* in_sizes, int n_in,
                              void* d_out, int out_size, void* d_ws, size_t ws_size,
                              hipStream_t stream) {
    const float* x    = (const float*)d_in[0];
    const float* cosp = (const float*)d_in[1];
    const float* sinp = (const float*)d_in[2];
    // d_in[3] = mask: unused by the reference computation
    const float* Wqkv = (const float*)d_in[4];
    const float* Wout = (const float*)d_in[5];
    float* out = (float*)d_out;

    char* ws = (char*)d_ws;
    float*  Qf    = (float*)(ws);                      // [ 0,16M)
    ushort* Kimg  = (ushort*)(ws + ((size_t)16<<20));  // [16,20M)
    ushort* Vimg  = (ushort*)(ws + ((size_t)20<<20));  // [20,24M)
    char*   Bo    = ws + ((size_t)24<<20);             // [24,28M)
    char*   Ximg  = ws + ((size_t)28<<20);             // [28,44M)  (dead after qkv-gemm)
    char*   Bq    = ws + ((size_t)44<<20);             // [44,50M)
    char*   Yimg  = ws + ((size_t)28<<20);             // [28,44M)  (over dead Ximg)

    // 1) input + weight images
    conv_xy<<<512, 256, 0, stream>>>(x, Ximg);
    conv_w<<<dim3(16, 12), 256, 0, stream>>>(Wqkv, FQKV, Bq);
    conv_w<<<dim3(16, 8), 256, 0, stream>>>(Wout, DEMBED, Bo);
    // 2) qkv projection + fused RoPE + K/V image build (round-2 config)
    gemm_qkv_mfma<<<dim3(12, 32), 256, 0, stream>>>(Ximg, Bq, cosp, sinp,
                                                    Qf, Kimg, Vimg);
    // 3) attention -> writes y's A-image directly (1024 blocks = 4/CU)
    attn10<<<1024, 256, 0, stream>>>(Qf, (const char*)Kimg, (const char*)Vimg,
                                     Yimg);
    // 4) out = y @ Wout
    gemm_out_mfma<<<dim3(8, 64), 256, 0, stream>>>(Yimg, Bo, out);
}